// Round 10
// baseline (187.946 us; speedup 1.0000x reference)
//
#include <hip/hip_runtime.h>
#include <stdint.h>

// B=32, D=64, H=64, W=64, K=512; N = B*H*W = 131072 tokens.
#define K_CODES 512
#define N_TOK   131072
#define ZQ_ELEMS 8388608   // 32*64*64*64
#define ZS_STRIDE 68       // floats: %4==0, %32==4 -> 2-way banks (free)
#define ECSTRIDE 65        // k_gather LDS stride

__device__ __forceinline__ uint32_t rotl32(uint32_t x, int d) {
#if __has_builtin(__builtin_amdgcn_alignbit)
  return __builtin_amdgcn_alignbit(x, x, 32 - d);
#else
  return (x << d) | (x >> (32 - d));
#endif
}

// ---- DPP wave(64) reduces: 6 VALU, no DS ops; total lands in lane 63 ----
template <int CTRL, int RMASK>
__device__ __forceinline__ float dpp_add_f32(float x) {
  int d = __builtin_amdgcn_update_dpp(0, __builtin_bit_cast(int, x),
                                      CTRL, RMASK, 0xf, true);  // 0-fill
  return x + __builtin_bit_cast(float, d);
}
template <int CTRL, int RMASK>
__device__ __forceinline__ float dpp_max_f32(float x) {
  int d = __builtin_amdgcn_update_dpp(0, __builtin_bit_cast(int, x),
                                      CTRL, RMASK, 0xf, true);  // 0-fill (all v>0)
  return fmaxf(x, __builtin_bit_cast(float, d));
}
template <int CTRL, int RMASK>
__device__ __forceinline__ uint32_t dpp_max_u32(uint32_t x) {
  uint32_t d = (uint32_t)__builtin_amdgcn_update_dpp(0, (int)x,
                                                     CTRL, RMASK, 0xf, true);
  return x > d ? x : d;
}
__device__ __forceinline__ float wave_sum(float x) {
  x = dpp_add_f32<0x111, 0xf>(x);
  x = dpp_add_f32<0x112, 0xf>(x);
  x = dpp_add_f32<0x114, 0xf>(x);
  x = dpp_add_f32<0x118, 0xf>(x);
  x = dpp_add_f32<0x142, 0xa>(x);
  x = dpp_add_f32<0x143, 0xc>(x);
  return __builtin_bit_cast(float,
      __builtin_amdgcn_readlane(__builtin_bit_cast(int, x), 63));
}
__device__ __forceinline__ float wave_fmax(float x) {
  x = dpp_max_f32<0x111, 0xf>(x);
  x = dpp_max_f32<0x112, 0xf>(x);
  x = dpp_max_f32<0x114, 0xf>(x);
  x = dpp_max_f32<0x118, 0xf>(x);
  x = dpp_max_f32<0x142, 0xa>(x);
  x = dpp_max_f32<0x143, 0xc>(x);
  return __builtin_bit_cast(float,
      __builtin_amdgcn_readlane(__builtin_bit_cast(int, x), 63));
}
__device__ __forceinline__ uint32_t wave_max_u32(uint32_t x) {
  x = dpp_max_u32<0x111, 0xf>(x);
  x = dpp_max_u32<0x112, 0xf>(x);
  x = dpp_max_u32<0x114, 0xf>(x);
  x = dpp_max_u32<0x118, 0xf>(x);
  x = dpp_max_u32<0x142, 0xa>(x);
  x = dpp_max_u32<0x143, 0xc>(x);
  return (uint32_t)__builtin_amdgcn_readlane((int)x, 63);
}
__device__ __forceinline__ float rl_f(float x, int L) {
  return __builtin_bit_cast(float,
      __builtin_amdgcn_readlane(__builtin_bit_cast(int, x), L));
}
__device__ __forceinline__ int rl_i(int x, int L) {
  return __builtin_amdgcn_readlane(x, L);
}

// JAX threefry2x32, key=(0,42), partitionable path: bits = out0^out1, counter=(0,lo).
__device__ __forceinline__ uint32_t tf_bits_xor(uint32_t lo) {
  const uint32_t ks0 = 0u, ks1 = 42u, ks2 = 0x1BD11BDAu ^ 0u ^ 42u;
  uint32_t x0 = 0u;
  uint32_t x1 = lo + ks1;
#define TFR(r) { x0 += x1; x1 = rotl32(x1, (r)); x1 ^= x0; }
  TFR(13) TFR(15) TFR(26) TFR(6)
  x0 += ks1; x1 += ks2 + 1u;
  TFR(17) TFR(29) TFR(16) TFR(24)
  x0 += ks2; x1 += ks0 + 2u;
  TFR(13) TFR(15) TFR(26) TFR(6)
  x0 += ks0; x1 += ks1 + 3u;
  TFR(17) TFR(29) TFR(16) TFR(24)
  x0 += ks1; x1 += ks2 + 4u;
  TFR(13) TFR(15) TFR(26) TFR(6)
  x0 += ks2; x1 += ks0 + 5u;
#undef TFR
  return x0 ^ x1;
}

// EXACT float sequence of the verified round-2 pass (rare fallback only).
__device__ __forceinline__ float g_of_u23(uint32_t u23) {
  float u0 = (float)u23 * 0x1p-23f;
  float u  = fmaxf(u0 + 1.17549435e-38f, 1.17549435e-38f);
  float nl = -logf(u);
  return -logf(nl);
}

// FAST gumbel: |g_fast - g_exact| <= ~1e-5 (Taylor near u~1 avoids abs-err blowup).
__device__ __forceinline__ float g_fast_u23(uint32_t u23) {
  uint32_t m = 8388608u - u23;
  float nl;
  if (m <= 131072u) {
    float x = (float)m * 0x1p-23f;      // exact
    nl = x * fmaf(x, fmaf(x, fmaf(x, 0.25f, 0.33333334f), 0.5f), 1.0f);
  } else {
    float u = (float)u23 * 0x1p-23f;
    nl = -__logf(u);
  }
  return -__logf(nl);
}

// FAST conservative packed threshold (pruning only; slack 64 u23-units).
__device__ __forceinline__ uint32_t thr_fast(float gthr) {
  float u_t = __expf(-__expf(-gthr));
  int B = (int)floorf(u_t * 8388608.0f) - 64;
  if (B < 0) B = 0;
  return ((uint32_t)B) << 9;
}

// ---------------- kernel 0: row-normalize codebook ----------------
__global__ void k_norm(const float* __restrict__ w, float* __restrict__ embn) {
  int k = blockIdx.x;
  int d = threadIdx.x;
  float v = w[(k << 6) + d];
  float s = v * v;
#pragma unroll
  for (int off = 1; off < 64; off <<= 1) s += __shfl_xor(s, off);
  embn[(k << 6) + d] = v / sqrtf(s);
}

// ---------------- kernel 1: wave-per-token, parallel-candidate argmax -------
// block = 1024 threads = 16 waves = 16 tokens; lane owns k in [8*lane, 8*lane+8)
// (lane order == k order, so lowest winning lane == first occurrence).
__global__ __launch_bounds__(1024, 8) void k_top(
    const float* __restrict__ z_e, const float* __restrict__ embn,
    const float* __restrict__ kappa_p, int* __restrict__ idx_ws,
    float* __restrict__ partials, float* __restrict__ out_idx) {
  __shared__ float zs[16 * ZS_STRIDE];
  __shared__ float redbuf[16];

  const float kappa = kappa_p[0];
  const int tid = threadIdx.x;
  const int wv = tid >> 6;
  const int lane = tid & 63;
  const int t0 = blockIdx.x * 16;
  const int t = t0 + wv;
  const int b = t0 >> 12, h = (t0 >> 6) & 63, w0 = t0 & 63;
  const float* zb = z_e + (b << 18) + (h << 6) + w0;

  // stage z: 1 coalesced load/thread
  {
    int wloc = tid & 15;
    int d = tid >> 4;
    zs[wloc * ZS_STRIDE + d] = zb[(d << 12) + wloc];
  }
  __syncthreads();
  const float zv = zs[wv * ZS_STRIDE + lane];   // z[t][d=lane]

  // broadcast helper: z[t][d] lives in lane d of this wave
#define ZR(d) rl_f(zv, d)

  // ---- phase 1: 8 threefry per lane ----
  const uint32_t base = ((uint32_t)t << 9) + (uint32_t)(lane << 3);
  uint32_t p[8];
  uint32_t rm = 0;
#pragma unroll
  for (int j = 0; j < 8; ++j) {
    uint32_t bits = tf_bits_xor(base + (uint32_t)j);
    uint32_t pk = (bits & 0xFFFFFE00u) | (uint32_t)((lane << 3) + j);
    p[j] = pk;
    rm = rm > pk ? rm : pk;
  }
  rm = wave_max_u32(rm);                // uniform

  // ---- cooperative seed eval of v(rmax): sets the cut ONLY ----
  {
    int k = (int)(rm & 511u);
    float e = embn[(k << 6) + lane];
    float pr = wave_sum(zv * e);
    float vseed = fmaf(kappa, pr, g_fast_u23(rm >> 9));
    // winner w: v_w >= v(rm) - slop  =>  g_w >= vseed - kappa - margins
    // (extra 1e-3 margin also covers seed-dot order vs canonical-dot order)
    uint32_t cut = thr_fast(vseed - 1.0001f * kappa - 0.001f);

    // ---- per-lane candidate mask (rm included naturally in its owner lane) --
    uint32_t msk = 0;
#pragma unroll
    for (int j = 0; j < 8; ++j) msk |= (p[j] >= cut) ? (1u << j) : 0u;

    // ---- parallel eval passes: one candidate per lane per pass ----
    float lv1 = -INFINITY, lv2 = -INFINITY;
    float ls1 = 0.f, ls2 = 0.f;
    int lk1 = 0, lk2 = 0;
    uint32_t lpk1 = 0, lpk2 = 0;

    while (__ballot(msk != 0u)) {
      bool have = (msk != 0u);
      // select lowest set j without runtime indexing (descending cndmask tree)
      uint32_t pk_sel = p[0];
#pragma unroll
      for (int j = 7; j >= 0; --j)
        if (msk & (1u << j)) pk_sel = p[j];
      msk &= msk - 1u;                      // clear lowest set bit

      int ck = have ? (int)(pk_sel & 511u) : 0;
      const float* ep = embn + (ck << 6);
      // canonical round-2 dot: 4 chains, z broadcast from registers (readlane)
      float s0 = 0.f, s1 = 0.f, s2 = 0.f, s3 = 0.f;
#pragma unroll
      for (int d = 0; d < 64; d += 4) {
        s0 = fmaf(ZR(d + 0), ep[d + 0], s0);
        s1 = fmaf(ZR(d + 1), ep[d + 1], s1);
        s2 = fmaf(ZR(d + 2), ep[d + 2], s2);
        s3 = fmaf(ZR(d + 3), ep[d + 3], s3);
      }
      float s = (s0 + s1) + (s2 + s3);
      float v = have ? fmaf(kappa, s, g_fast_u23(pk_sel >> 9)) : -INFINITY;
      // per-lane top-2 (ascending j => ascending k; strict > keeps min-k)
      if (v > lv1) {
        lv2 = lv1; ls2 = ls1; lk2 = lk1; lpk2 = lpk1;
        lv1 = v;   ls1 = s;   lk1 = ck;  lpk1 = pk_sel;
      } else if (v > lv2) {
        lv2 = v; ls2 = s; lk2 = ck; lpk2 = pk_sel;
      }
    }

    // ---- wave reduce: argmax with first-occurrence (lane order == k order) --
    float v1 = wave_fmax(lv1);                       // uniform
    unsigned long long ball = __ballot(lv1 == v1);
    int Ls = (int)(__ffsll(ball) - 1);               // lowest lane = lowest k
    int   bk   = rl_i(lk1, Ls);
    float bsim = rl_f(ls1, Ls);
    uint32_t bpk = (uint32_t)rl_i((int)lpk1, Ls);

    // runner-up (for ambiguity gap): best of (other lanes' lv1, Ls's lv2)
    float lv1m = (lane == Ls) ? -INFINITY : lv1;
    float v2a = wave_fmax(lv1m);
    float v2b = rl_f(lv2, Ls);
    float v2 = fmaxf(v2a, v2b);

    // ---- rare ambiguity fallback: precise g, first-occurrence tie-break ----
    if (v1 - v2 < 2e-4f) {
      int k2; float s2; uint32_t pk2;
      if (v2a >= v2b) {
        unsigned long long b2 = __ballot(lv1m == v2a);
        int L2 = (int)(__ffsll(b2) - 1);
        k2 = rl_i(lk1, L2); s2 = rl_f(ls1, L2); pk2 = (uint32_t)rl_i((int)lpk1, L2);
      } else {
        k2 = rl_i(lk2, Ls); s2 = rl_f(ls2, Ls); pk2 = (uint32_t)rl_i((int)lpk2, Ls);
      }
      if (v2 > -INFINITY) {
        float vp1 = fmaf(kappa, bsim, g_of_u23(bpk >> 9));
        float vp2 = fmaf(kappa, s2,   g_of_u23(pk2 >> 9));
        if (vp2 > vp1 || (vp2 == vp1 && k2 < bk)) { bk = k2; bsim = s2; }
      }
    }

    if (lane == 0) {
      idx_ws[t] = bk;
      out_idx[t] = (float)bk;
      redbuf[wv] = kappa * (1.0f - bsim);
    }
  }
#undef ZR
  __syncthreads();
  if (tid == 0) {
    float s = 0.f;
#pragma unroll
    for (int i = 0; i < 16; ++i) s += redbuf[i];
    partials[blockIdx.x] = s;
  }
}

// ---------------- kernel 2: reduce 8192 partials -> reg ----------------
__global__ __launch_bounds__(256) void k_reg(const float* __restrict__ partials,
                                             float* __restrict__ out_reg) {
  int tid = threadIdx.x;
  float s = 0.f;
#pragma unroll
  for (int j = 0; j < 32; ++j) s += partials[(j << 8) + tid];
#pragma unroll
  for (int off = 32; off; off >>= 1) s += __shfl_down(s, off);
  __shared__ float l[4];
  int lane = tid & 63, wid = tid >> 6;
  if (lane == 0) l[wid] = s;
  __syncthreads();
  if (tid == 0) out_reg[0] = ((l[0] + l[1]) + (l[2] + l[3])) * (1.0f / 131072.0f);
}

// ---------------- kernel 3: gather z_q via LDS transpose ----------------
__global__ __launch_bounds__(256) void k_gather(
    const float* __restrict__ embn, const int* __restrict__ idx_ws,
    float* __restrict__ out_zq) {
  __shared__ float erow[64 * ECSTRIDE];
  __shared__ int sidx[64];
  int blk = blockIdx.x;
  int b = blk >> 6, h = blk & 63;
  int tid = threadIdx.x;
  int lane = tid & 63, wid = tid >> 6;

  if (tid < 64) sidx[tid] = idx_ws[(b << 12) + (h << 6) + tid];
  __syncthreads();
  for (int r = wid; r < 64; r += 4)
    erow[r * ECSTRIDE + lane] = embn[(sidx[r] << 6) + lane];
  __syncthreads();

  int w = tid & 63;
  int d0 = tid >> 6;
  float* outp = out_zq + (b << 18) + (h << 6) + w;
#pragma unroll
  for (int i = 0; i < 16; ++i) {
    int d = (i << 2) + d0;
    outp[d << 12] = erow[w * ECSTRIDE + d];
  }
}

extern "C" void kernel_launch(void* const* d_in, const int* in_sizes, int n_in,
                              void* d_out, int out_size, void* d_ws, size_t ws_size,
                              hipStream_t stream) {
  const float* z_e    = (const float*)d_in[0];
  const float* emb_w  = (const float*)d_in[1];
  const float* kappa  = (const float*)d_in[2];

  float* embn     = (float*)d_ws;                              // 32768 f32
  int*   idx_ws   = (int*)((char*)d_ws + 131072);              // 131072 i32
  float* partials = (float*)((char*)d_ws + 131072 + 524288);   // 8192 f32

  float* out     = (float*)d_out;
  float* out_zq  = out;                    // [8388608]
  float* out_reg = out + ZQ_ELEMS;         // [1]
  float* out_idx = out + ZQ_ELEMS + 1;     // [131072]

  k_norm  <<<K_CODES, 64, 0, stream>>>(emb_w, embn);
  k_top   <<<N_TOK / 16, 1024, 0, stream>>>(z_e, embn, kappa, idx_ws, partials, out_idx);
  k_reg   <<<1, 256, 0, stream>>>(partials, out_reg);
  k_gather<<<2048, 256, 0, stream>>>(embn, idx_ws, out_zq);
}

// Round 11
// 160.111 us; speedup vs baseline: 1.1739x; 1.1739x over previous
//
#include <hip/hip_runtime.h>
#include <stdint.h>

// B=32, D=64, H=64, W=64, K=512; N = B*H*W = 131072 tokens.
#define K_CODES 512
#define N_TOK   131072
#define ZQ_ELEMS 8388608   // 32*64*64*64
#define ZS_STRIDE 68       // floats: %4==0, %32==4 -> 2-way banks (free)
#define ECSTRIDE 65        // k_gather LDS stride

__device__ __forceinline__ uint32_t rotl32(uint32_t x, int d) {
#if __has_builtin(__builtin_amdgcn_alignbit)
  return __builtin_amdgcn_alignbit(x, x, 32 - d);
#else
  return (x << d) | (x >> (32 - d));
#endif
}

// ---- DPP wave(64) reduces: 6 VALU, no DS ops; total lands in lane 63 ----
template <int CTRL, int RMASK>
__device__ __forceinline__ float dpp_add_f32(float x) {
  int d = __builtin_amdgcn_update_dpp(0, __builtin_bit_cast(int, x),
                                      CTRL, RMASK, 0xf, true);  // 0-fill
  return x + __builtin_bit_cast(float, d);
}
template <int CTRL, int RMASK>
__device__ __forceinline__ uint32_t dpp_max_u32(uint32_t x) {
  uint32_t d = (uint32_t)__builtin_amdgcn_update_dpp(0, (int)x,
                                                     CTRL, RMASK, 0xf, true);
  return x > d ? x : d;
}
__device__ __forceinline__ float wave_sum(float x) {
  x = dpp_add_f32<0x111, 0xf>(x);   // row_shr:1
  x = dpp_add_f32<0x112, 0xf>(x);   // row_shr:2
  x = dpp_add_f32<0x114, 0xf>(x);   // row_shr:4
  x = dpp_add_f32<0x118, 0xf>(x);   // row_shr:8
  x = dpp_add_f32<0x142, 0xa>(x);   // row_bcast:15 -> rows 1,3
  x = dpp_add_f32<0x143, 0xc>(x);   // row_bcast:31 -> rows 2,3
  return __builtin_bit_cast(float,
      __builtin_amdgcn_readlane(__builtin_bit_cast(int, x), 63));
}
__device__ __forceinline__ uint32_t wave_max_u32(uint32_t x) {
  x = dpp_max_u32<0x111, 0xf>(x);
  x = dpp_max_u32<0x112, 0xf>(x);
  x = dpp_max_u32<0x114, 0xf>(x);
  x = dpp_max_u32<0x118, 0xf>(x);
  x = dpp_max_u32<0x142, 0xa>(x);
  x = dpp_max_u32<0x143, 0xc>(x);
  return (uint32_t)__builtin_amdgcn_readlane((int)x, 63);
}
// dynamic-lane broadcast via v_readlane (SGPR lane idx) — no DS, no waits
__device__ __forceinline__ uint32_t rl_u32(uint32_t x, int L) {
  return (uint32_t)__builtin_amdgcn_readlane((int)x, L);
}

// JAX threefry2x32, key=(0,42), partitionable path: bits = out0^out1, counter=(0,lo).
__device__ __forceinline__ uint32_t tf_bits_xor(uint32_t lo) {
  const uint32_t ks0 = 0u, ks1 = 42u, ks2 = 0x1BD11BDAu ^ 0u ^ 42u;
  uint32_t x0 = 0u;
  uint32_t x1 = lo + ks1;
#define TFR(r) { x0 += x1; x1 = rotl32(x1, (r)); x1 ^= x0; }
  TFR(13) TFR(15) TFR(26) TFR(6)
  x0 += ks1; x1 += ks2 + 1u;
  TFR(17) TFR(29) TFR(16) TFR(24)
  x0 += ks2; x1 += ks0 + 2u;
  TFR(13) TFR(15) TFR(26) TFR(6)
  x0 += ks0; x1 += ks1 + 3u;
  TFR(17) TFR(29) TFR(16) TFR(24)
  x0 += ks1; x1 += ks2 + 4u;
  TFR(13) TFR(15) TFR(26) TFR(6)
  x0 += ks2; x1 += ks0 + 5u;
#undef TFR
  return x0 ^ x1;
}

// EXACT float sequence of the verified round-2 pass (rare fallback only).
__device__ __forceinline__ float g_of_u23(uint32_t u23) {
  float u0 = (float)u23 * 0x1p-23f;
  float u  = fmaxf(u0 + 1.17549435e-38f, 1.17549435e-38f);
  float nl = -logf(u);
  return -logf(nl);
}

// FAST gumbel: |g_fast - g_exact| <= ~1e-5 (Taylor near u~1 avoids abs-err blowup).
__device__ __forceinline__ float g_fast_u23(uint32_t u23) {
  uint32_t m = 8388608u - u23;
  float nl;
  if (m <= 131072u) {
    float x = (float)m * 0x1p-23f;      // exact
    nl = x * fmaf(x, fmaf(x, fmaf(x, 0.25f, 0.33333334f), 0.5f), 1.0f);
  } else {
    float u = (float)u23 * 0x1p-23f;
    nl = -__logf(u);
  }
  return -__logf(nl);
}

// FAST conservative packed threshold (pruning only; slack 64 u23-units).
__device__ __forceinline__ uint32_t thr_fast(float gthr) {
  float u_t = __expf(-__expf(-gthr));
  int B = (int)floorf(u_t * 8388608.0f) - 64;
  if (B < 0) B = 0;
  return ((uint32_t)B) << 9;
}

// ---------------- kernel 0: row-normalize codebook ----------------
__global__ void k_norm(const float* __restrict__ w, float* __restrict__ embn) {
  int k = blockIdx.x;
  int d = threadIdx.x;
  float v = w[(k << 6) + d];
  float s = v * v;
#pragma unroll
  for (int off = 1; off < 64; off <<= 1) s += __shfl_xor(s, off);
  embn[(k << 6) + d] = v / sqrtf(s);
}

// ---------------- kernel 1: wave-per-token cooperative gumbel argmax --------
// block = 1024 threads = 16 waves = 16 tokens; lane = channel d;
// each lane owns 8 consecutive k in registers.
__global__ __launch_bounds__(1024, 8) void k_top(
    const float* __restrict__ z_e, const float* __restrict__ embn,
    const float* __restrict__ kappa_p, int* __restrict__ idx_ws,
    float* __restrict__ partials, float* __restrict__ out_idx) {
  __shared__ float zs[16 * ZS_STRIDE];
  __shared__ float redbuf[16];

  const float kappa = kappa_p[0];
  const int tid = threadIdx.x;
  const int wv = tid >> 6;
  const int lane = tid & 63;
  const int t0 = blockIdx.x * 16;
  const int t = t0 + wv;
  const int b = t0 >> 12, h = (t0 >> 6) & 63, w0 = t0 & 63;
  const float* zb = z_e + (b << 18) + (h << 6) + w0;

  // stage z: 1 coalesced load/thread
  {
    int wloc = tid & 15;
    int d = tid >> 4;
    zs[wloc * ZS_STRIDE + d] = zb[(d << 12) + wloc];
  }
  __syncthreads();
  const float zv = zs[wv * ZS_STRIDE + lane];   // z[t][d=lane]

  // ---- phase 1: 8 threefry per lane, all packed values in registers ----
  const uint32_t base = ((uint32_t)t << 9) + (uint32_t)(lane << 3);
  uint32_t p[8];
  uint32_t rm = 0;
#pragma unroll
  for (int j = 0; j < 8; ++j) {
    uint32_t bits = tf_bits_xor(base + (uint32_t)j);
    uint32_t pk = (bits & 0xFFFFFE00u) | (uint32_t)((lane << 3) + j);
    p[j] = pk;
    rm = rm > pk ? rm : pk;
  }
  rm = wave_max_u32(rm);                // uniform

  const float margin = fmaf(1.0001f, kappa, 0.001f);  // hoisted

  // ---- seed: eval v(rmax) with FAST g; seeds argmax state and the cut ----
  float best, bsim, best2 = -INFINITY;
  int bk;
  {
    int k = (int)(rm & 511u);
    float e = embn[(k << 6) + lane];          // coalesced 256 B, L2-hot
    float pr = wave_sum(zv * e);              // uniform
    best = fmaf(kappa, pr, g_fast_u23(rm >> 9));
    bsim = pr;
    bk = k;
  }
  const uint32_t cut = thr_fast(best - margin);   // fixed cut (no tightening)

  // ---- phase 2: ballot-enumerated FAST evals (readlane broadcast, no DS) ----
#pragma unroll
  for (int j = 0; j < 8; ++j) {               // static j -> p[j] stays in VGPR
    unsigned long long m = __ballot(p[j] >= cut);
    while (m) {
      int L = (int)(__ffsll(m) - 1);
      m &= m - 1;
      uint32_t pk = rl_u32(p[j], L);          // SGPR-lane broadcast, no DS
      if (pk == rm) continue;                 // already evaluated (uniform)
      int k = (int)(pk & 511u);
      float e = embn[(k << 6) + lane];
      float pr = wave_sum(zv * e);            // uniform
      float v = fmaf(kappa, pr, g_fast_u23(pk >> 9));
      if (v > best) {
        best2 = best;
        best = v; bk = k; bsim = pr;
      } else if (v > best2) {
        best2 = v;                            // includes v==best (gap 0 -> fallback)
      }
    }
  }

  // ---- rare ambiguity fallback (~1e-4 of tokens): exact round-7 semantics ----
  if (best - best2 < 2e-4f) {
    best = -INFINITY; bsim = 0.0f; bk = 0;
#pragma unroll
    for (int j = 0; j < 8; ++j) {
      unsigned long long m = __ballot(p[j] >= cut);
      while (m) {
        int L = (int)(__ffsll(m) - 1);
        m &= m - 1;
        uint32_t pk = rl_u32(p[j], L);
        int k = (int)(pk & 511u);
        float e = embn[(k << 6) + lane];
        float pr = wave_sum(zv * e);
        float gg = g_of_u23(pk >> 9);         // precise (feeds comparisons)
        float v = fmaf(kappa, pr, gg);
        if (v > best || (v == best && k < bk)) { best = v; bk = k; bsim = pr; }
      }
    }
  }

  if (lane == 0) {
    idx_ws[t] = bk;
    out_idx[t] = (float)bk;
    redbuf[wv] = kappa * (1.0f - bsim);
  }
  __syncthreads();
  if (tid == 0) {
    float s = 0.f;
#pragma unroll
    for (int i = 0; i < 16; ++i) s += redbuf[i];
    partials[blockIdx.x] = s;
  }
}

// ---------------- kernel 2: reduce 8192 partials -> reg ----------------
__global__ __launch_bounds__(256) void k_reg(const float* __restrict__ partials,
                                             float* __restrict__ out_reg) {
  int tid = threadIdx.x;
  float s = 0.f;
#pragma unroll
  for (int j = 0; j < 32; ++j) s += partials[(j << 8) + tid];
#pragma unroll
  for (int off = 32; off; off >>= 1) s += __shfl_down(s, off);
  __shared__ float l[4];
  int lane = tid & 63, wid = tid >> 6;
  if (lane == 0) l[wid] = s;
  __syncthreads();
  if (tid == 0) out_reg[0] = ((l[0] + l[1]) + (l[2] + l[3])) * (1.0f / 131072.0f);
}

// ---------------- kernel 3: gather z_q via LDS transpose ----------------
__global__ __launch_bounds__(256) void k_gather(
    const float* __restrict__ embn, const int* __restrict__ idx_ws,
    float* __restrict__ out_zq) {
  __shared__ float erow[64 * ECSTRIDE];
  __shared__ int sidx[64];
  int blk = blockIdx.x;
  int b = blk >> 6, h = blk & 63;
  int tid = threadIdx.x;
  int lane = tid & 63, wid = tid >> 6;

  if (tid < 64) sidx[tid] = idx_ws[(b << 12) + (h << 6) + tid];
  __syncthreads();
  for (int r = wid; r < 64; r += 4)
    erow[r * ECSTRIDE + lane] = embn[(sidx[r] << 6) + lane];
  __syncthreads();

  int w = tid & 63;
  int d0 = tid >> 6;
  float* outp = out_zq + (b << 18) + (h << 6) + w;
#pragma unroll
  for (int i = 0; i < 16; ++i) {
    int d = (i << 2) + d0;
    outp[d << 12] = erow[w * ECSTRIDE + d];
  }
}

extern "C" void kernel_launch(void* const* d_in, const int* in_sizes, int n_in,
                              void* d_out, int out_size, void* d_ws, size_t ws_size,
                              hipStream_t stream) {
  const float* z_e    = (const float*)d_in[0];
  const float* emb_w  = (const float*)d_in[1];
  const float* kappa  = (const float*)d_in[2];

  float* embn     = (float*)d_ws;                              // 32768 f32
  int*   idx_ws   = (int*)((char*)d_ws + 131072);              // 131072 i32
  float* partials = (float*)((char*)d_ws + 131072 + 524288);   // 8192 f32

  float* out     = (float*)d_out;
  float* out_zq  = out;                    // [8388608]
  float* out_reg = out + ZQ_ELEMS;         // [1]
  float* out_idx = out + ZQ_ELEMS + 1;     // [131072]

  k_norm  <<<K_CODES, 64, 0, stream>>>(emb_w, embn);
  k_top   <<<N_TOK / 16, 1024, 0, stream>>>(z_e, embn, kappa, idx_ws, partials, out_idx);
  k_reg   <<<1, 256, 0, stream>>>(partials, out_reg);
  k_gather<<<2048, 256, 0, stream>>>(embn, idx_ws, out_zq);
}